// Round 9
// baseline (506.880 us; speedup 1.0000x reference)
//
#include <hip/hip_runtime.h>
#include <hip/hip_cooperative_groups.h>

namespace cg = cooperative_groups;

#define N_EVENTS 16384
#define DIM 128
#define NK 9
#define NSEQ 2048
#define TT 147456
#define CHUNK 64
#define NBLK 256
#define TPB 512
#define TOKB 576            // TT / NBLK

typedef __attribute__((ext_vector_type(8))) short bf16x8;
typedef __attribute__((ext_vector_type(4))) float f32x4;
typedef __attribute__((ext_vector_type(4))) int i32x4;

// ---- workspace layout (bytes) ----
#define OFF_EV     0UL
#define OFF_WC     (OFF_EV   + (size_t)N_EVENTS*DIM*2)
#define OFF_SCAT   (OFF_WC   + (size_t)512*256*2)
#define OFF_GATH   (OFF_SCAT + (size_t)NK*DIM*DIM*2)
#define OFF_XS     (OFF_GATH + (size_t)NK*DIM*DIM*2)
#define OFF_HS     (OFF_XS   + (size_t)TT*DIM*2)
#define OFF_KLIST  (OFF_HS   + (size_t)TT*DIM*2)
#define OFF_ACC    (OFF_KLIST+ (size_t)TT*4)
#define OFF_SEQOFF (OFF_ACC  + (size_t)N_EVENTS*DIM*4)
#define OFF_GROUP  (OFF_SEQOFF + (size_t)NSEQ*4)
#define OFF_MISC   (OFF_GROUP  + (size_t)NSEQ*4)
#define OFF_BH     (OFF_MISC   + 256UL)
// misc ints: [0..8]=kcount  [32..40]=koff  [48..57]=choff

struct MegaParams {
    const float *ev, *sw, *gw, *wih, *whh, *lng, *lnb;
    const int *pos, *orig, *lens;
    short *evb, *wcb, *swb, *gwb, *xs, *hs;
    int *klist, *misc, *bh, *seqo, *grp;
    float *acc, *out;
};

__device__ __forceinline__ short f2b(float f) {
    union { float f; unsigned u; } v; v.f = f;
    unsigned r = (v.u + 0x7FFFu + ((v.u >> 16) & 1u)) >> 16;
    return (short)r;
}
// raw v_rcp_f32 — avoids HIP's ~10-instr IEEE divide (the R8 win)
__device__ __forceinline__ float fsig(float x) {
    return __builtin_amdgcn_rcpf(1.f + __expf(-x));
}
__device__ __forceinline__ float ftanh(float x) {
    return 1.f - 2.f * __builtin_amdgcn_rcpf(__expf(2.f * x) + 1.f);
}

#define MF(a, b, c) __builtin_amdgcn_mfma_f32_16x16x32_bf16(a, b, c, 0, 0, 0)

// one chunk of the bucketed position-projection GEMM, 512-thread version
// mode 0: rows = evb[orig[tok]] -> bf16 out rows xs[tok]
// mode 1: rows = hs[tok]        -> atomicAdd f32 C into acc[orig[tok]]
__device__ __forceinline__ void bucket_chunk(
        int c, const int* choff, const short* src, const short* wall,
        const int* klist, const int* misc, const int* orig,
        short* xs_out, float* acc, int mode,
        int* tok, int* dst, short* A, int tid) {
    int k = 0;
    #pragma unroll
    for (int j = 1; j < NK; j++) k += (choff[j] <= c) ? 1 : 0;
    int lc = c - choff[k];
    int cnt = misc[k];
    int base = misc[32 + k] + lc * CHUNK;
    int nv = min(CHUNK, cnt - lc * CHUNK);
    if (tid < CHUNK) {
        int tv = klist[base + ((tid < nv) ? tid : 0)];
        tok[tid] = tv;
        dst[tid] = orig[tv];
    }
    __syncthreads();
    {
        int row = tid >> 3, part = tid & 7;          // 64 rows x 8 parts of 32B
        int ridx = (mode == 0) ? dst[row] : tok[row];
        const i32x4* s4 = (const i32x4*)(src + (size_t)ridx * DIM + part * 16);
        i32x4* d4 = (i32x4*)(A + row * 136 + part * 16);
        d4[0] = s4[0]; d4[1] = s4[1];
    }
    __syncthreads();
    int w = tid >> 6, lane = tid & 63, l15 = lane & 15, q = lane >> 4;
    const short* wk = wall + (size_t)k * DIM * DIM;
    int h = w * 16 + l15;                            // wave owns 16 cols
    bf16x8 Bfr[4];
    #pragma unroll
    for (int kt = 0; kt < 4; kt++)
        Bfr[kt] = *(const bf16x8*)(wk + h * DIM + kt * 32 + q * 8);
    f32x4 C[4];
    #pragma unroll
    for (int mt = 0; mt < 4; mt++) C[mt] = (f32x4){0.f, 0.f, 0.f, 0.f};
    #pragma unroll
    for (int mt = 0; mt < 4; mt++) {
        const short* ar = A + (mt * 16 + l15) * 136 + q * 8;
        bf16x8 A0 = *(const bf16x8*)(ar);
        bf16x8 A1 = *(const bf16x8*)(ar + 32);
        bf16x8 A2 = *(const bf16x8*)(ar + 64);
        bf16x8 A3 = *(const bf16x8*)(ar + 96);
        C[mt] = MF(A0, Bfr[0], C[mt]);
        C[mt] = MF(A1, Bfr[1], C[mt]);
        C[mt] = MF(A2, Bfr[2], C[mt]);
        C[mt] = MF(A3, Bfr[3], C[mt]);
    }
    if (mode == 0) {
        __syncthreads();
        #pragma unroll
        for (int mt = 0; mt < 4; mt++)
            #pragma unroll
            for (int r = 0; r < 4; r++)
                A[(mt * 16 + q * 4 + r) * 136 + h] = f2b(C[mt][r]);
        __syncthreads();
        int row = tid >> 3, part = tid & 7;
        if (row < nv) {
            const i32x4* s4 = (const i32x4*)(A + row * 136 + part * 16);
            i32x4* d4 = (i32x4*)(xs_out + (size_t)tok[row] * DIM + part * 16);
            d4[0] = s4[0]; d4[1] = s4[1];
        }
        __syncthreads();
    } else {
        #pragma unroll
        for (int mt = 0; mt < 4; mt++)
            #pragma unroll
            for (int r = 0; r < 4; r++) {
                int row = mt * 16 + q * 4 + r;
                if (row < nv)
                    atomicAdd(acc + (size_t)dst[row] * DIM + h, C[mt][r]);
            }
        __syncthreads();
    }
}

// One LSTM step, compile-time slot J (0..7) — v8 verbatim.
#define LSTM_STEP(J, PF) { \
    const int i_ = ib8 + (J); \
    f32x4 Cxi = {0.f,0.f,0.f,0.f}, Cxf = {0.f,0.f,0.f,0.f}; \
    f32x4 Cxg = {0.f,0.f,0.f,0.f}, Cxo = {0.f,0.f,0.f,0.f}; \
    Cxi = MF(PF[0], Bf[0][0], Cxi); Cxf = MF(PF[0], Bf[1][0], Cxf); \
    Cxg = MF(PF[0], Bf[2][0], Cxg); Cxo = MF(PF[0], Bf[3][0], Cxo); \
    Cxi = MF(PF[1], Bf[0][1], Cxi); Cxf = MF(PF[1], Bf[1][1], Cxf); \
    Cxg = MF(PF[1], Bf[2][1], Cxg); Cxo = MF(PF[1], Bf[3][1], Cxo); \
    Cxi = MF(PF[2], Bf[0][2], Cxi); Cxf = MF(PF[2], Bf[1][2], Cxf); \
    Cxg = MF(PF[2], Bf[2][2], Cxg); Cxo = MF(PF[2], Bf[3][2], Cxo); \
    Cxi = MF(PF[3], Bf[0][3], Cxi); Cxf = MF(PF[3], Bf[1][3], Cxf); \
    Cxg = MF(PF[3], Bf[2][3], Cxg); Cxo = MF(PF[3], Bf[3][3], Cxo); \
    bf16x8 Hf0, Hf1, Hf2, Hf3; \
    { const short* hp_ = hb + (((J) + 7) & 7) * 1088 + l15 * 136 + ql * 8; \
      Hf0 = *(const bf16x8*)(hp_);      Hf1 = *(const bf16x8*)(hp_ + 32); \
      Hf2 = *(const bf16x8*)(hp_ + 64); Hf3 = *(const bf16x8*)(hp_ + 96); } \
    f32x4 Chi = {0.f,0.f,0.f,0.f}, Chf = {0.f,0.f,0.f,0.f}; \
    f32x4 Chg = {0.f,0.f,0.f,0.f}, Cho = {0.f,0.f,0.f,0.f}; \
    Chi = MF(Hf0, Bf[0][4], Chi); Chf = MF(Hf0, Bf[1][4], Chf); \
    Chg = MF(Hf0, Bf[2][4], Chg); Cho = MF(Hf0, Bf[3][4], Cho); \
    Chi = MF(Hf1, Bf[0][5], Chi); Chf = MF(Hf1, Bf[1][5], Chf); \
    Chg = MF(Hf1, Bf[2][5], Chg); Cho = MF(Hf1, Bf[3][5], Cho); \
    Chi = MF(Hf2, Bf[0][6], Chi); Chf = MF(Hf2, Bf[1][6], Chf); \
    Chg = MF(Hf2, Bf[2][6], Chg); Cho = MF(Hf2, Bf[3][6], Cho); \
    Chi = MF(Hf3, Bf[0][7], Chi); Chf = MF(Hf3, Bf[1][7], Chf); \
    Chg = MF(Hf3, Bf[2][7], Chg); Cho = MF(Hf3, Bf[3][7], Cho); \
    if (l15 < 8) { \
        const short* xp_ = xsl + xoff; \
        PF[0] = *(const bf16x8*)(xp_);      PF[1] = *(const bf16x8*)(xp_ + 32); \
        PF[2] = *(const bf16x8*)(xp_ + 64); PF[3] = *(const bf16x8*)(xp_ + 96); \
    } \
    xoff += ((i_ + 4) <= my_len) ? DIM : 0; \
    f32x4 Gi = Cxi + Chi, Gf = Cxf + Chf, Gg = Cxg + Chg, Go = Cxo + Cho; \
    { \
        int src_ = lane & 31; \
        float i2 = __shfl(Gi[2], src_, 64), i3 = __shfl(Gi[3], src_, 64); \
        float f2 = __shfl(Gf[2], src_, 64), f3 = __shfl(Gf[3], src_, 64); \
        float g2 = __shfl(Gg[2], src_, 64), g3 = __shfl(Gg[3], src_, 64); \
        float o2 = __shfl(Go[2], src_, 64), o3 = __shfl(Go[3], src_, 64); \
        float iA = lo ? Gi[0] : i2, iB = lo ? Gi[1] : i3; \
        float fA = lo ? Gf[0] : f2, fB = lo ? Gf[1] : f3; \
        float gA = lo ? Gg[0] : g2, gB = lo ? Gg[1] : g3; \
        float oA = lo ? Go[0] : o2, oB = lo ? Go[1] : o3; \
        if (i_ < lenA) { \
            float si = fsig(iA), sf = fsig(fA), so = fsig(oA); \
            float tg = ftanh(gA); \
            float cn = sf * cA + si * tg; \
            float th = ftanh(cn); \
            cA = cn; \
            hb[(J) * 1088 + rowA * 136 + u] = f2b(so * th); \
        } \
        if (i_ < lenB) { \
            float si = fsig(iB), sf = fsig(fB), so = fsig(oB); \
            float tg = ftanh(gB); \
            float cn = sf * cB + si * tg; \
            float th = ftanh(cn); \
            cB = cn; \
            hb[(J) * 1088 + rowB * 136 + u] = f2b(so * th); \
        } \
    } \
    __syncthreads(); \
}

// Whole pipeline in ONE cooperative launch: each dispatch boundary previously
// cost ~12-15 us of dead time (9 launches -> ~125 us, 40% of R8's total).
__global__ __launch_bounds__(TPB, 2) void mega_kernel(MegaParams p) {
    cg::grid_group grid = cg::this_grid();
    __shared__ int hist9[NK];
    __shared__ int hsc[NBLK * NK];
    __shared__ int cnt9[NK];
    __shared__ int lensS[NSEQ];
    __shared__ int tsum[256], tlong[256];
    __shared__ int offb[NK];
    __shared__ int tok[CHUNK], dst[CHUNK];
    __shared__ short Atile[CHUNK * 136];
    __shared__ short hchunk[11 * 8 * 136];
    __shared__ int s_off[8], s_len[8];

    const int bid = blockIdx.x, tid = threadIdx.x;
    const int gtid = bid * TPB + tid;

    // ---------- Phase A: convert to bf16 + zero acc + per-block pos histogram ----------
    for (int i = gtid; i < N_EVENTS * DIM; i += NBLK * TPB) {
        p.evb[i] = f2b(p.ev[i]);
        p.acc[i] = 0.f;
    }
    if (gtid < 512 * DIM) {
        int j = gtid >> 7, d = gtid & 127;
        p.wcb[j * 256 + d]       = f2b(p.wih[gtid]);
        p.wcb[j * 256 + 128 + d] = f2b(p.whh[gtid]);
    }
    for (int i = gtid; i < NK * DIM * DIM; i += NBLK * TPB) {
        p.swb[i] = f2b(p.sw[i]);
        p.gwb[i] = f2b(p.gw[i]);
    }
    if (tid < NK) hist9[tid] = 0;
    __syncthreads();
    {
        int t0 = bid * TOKB + tid;
        atomicAdd(&hist9[p.pos[t0]], 1);
        if (tid < TOKB - TPB) atomicAdd(&hist9[p.pos[t0 + TPB]], 1);
    }
    __syncthreads();
    if (tid < NK) p.bh[bid * NK + tid] = hist9[tid];
    grid.sync();

    // ---------- Phase B: block 0 = bin scan; block 1 = sequence setup ----------
    if (bid == 0) {
        for (int i = tid; i < NBLK * NK; i += TPB) hsc[i] = p.bh[i];
        __syncthreads();
        if (tid < NK) {
            int run = 0;
            for (int b = 0; b < NBLK; b++) {
                int v = hsc[b * NK + tid];
                hsc[b * NK + tid] = run;
                run += v;
            }
            cnt9[tid] = run;
            p.misc[tid] = run;
        }
        __syncthreads();
        if (tid == 0) {
            int ko = 0, co = 0;
            for (int k = 0; k < NK; k++) {
                int c = cnt9[k];
                p.misc[32 + k] = ko;
                p.misc[48 + k] = co;
                ko += c;
                co += (c + CHUNK - 1) / CHUNK;
            }
            p.misc[48 + NK] = co;
        }
        for (int i = tid; i < NBLK * NK; i += TPB) p.bh[i] = hsc[i];
    }
    if (bid == 1) {
        for (int i = tid; i < NSEQ; i += TPB) lensS[i] = p.lens[i];
        __syncthreads();
        int base = tid * 8;
        int ls[8]; int s = 0, lc = 0;
        if (tid < 256) {
            #pragma unroll
            for (int i = 0; i < 8; i++) {
                ls[i] = lensS[base + i]; s += ls[i]; lc += (ls[i] > 64) ? 1 : 0;
            }
            tsum[tid] = s; tlong[tid] = lc;
        }
        __syncthreads();
        for (int d = 1; d < 256; d <<= 1) {
            int a = 0, b = 0;
            if (tid < 256 && tid >= d) { a = tsum[tid - d]; b = tlong[tid - d]; }
            __syncthreads();
            if (tid < 256) { tsum[tid] += a; tlong[tid] += b; }
            __syncthreads();
        }
        if (tid < 256) {
            int nlong_total = tlong[255];
            int excl = tsum[tid] - s;
            int excl_long = tlong[tid] - lc;
            int run = 0, runl = 0;
            #pragma unroll
            for (int i = 0; i < 8; i++) {
                int sid = base + i;
                p.seqo[sid] = excl + run;
                int lb = excl_long + runl;
                if (ls[i] > 64) { p.grp[lb] = sid; runl++; }
                else            { p.grp[nlong_total + (sid - lb)] = sid; }
                run += ls[i];
            }
        }
    }
    grid.sync();

    // ---------- Phase C: fill klist (LDS-atomic rank per block) ----------
    if (tid < NK) offb[tid] = p.misc[32 + tid] + p.bh[bid * NK + tid];
    __syncthreads();
    {
        int t0 = bid * TOKB + tid;
        int pos0 = p.pos[t0];
        int r0 = atomicAdd(&offb[pos0], 1);
        p.klist[r0] = t0;
        if (tid < TOKB - TPB) {
            int t1 = t0 + TPB;
            int pos1 = p.pos[t1];
            int r1 = atomicAdd(&offb[pos1], 1);
            p.klist[r1] = t1;
        }
    }
    grid.sync();

    // ---------- Phase D: scatter projection (bucketed GEMM, mode 0) ----------
    {
        int choff[NK + 1];
        #pragma unroll
        for (int j = 0; j <= NK; j++) choff[j] = p.misc[48 + j];
        int nchunks = choff[NK];
        for (int c = bid; c < nchunks; c += NBLK)
            bucket_chunk(c, choff, p.evb, p.swb, p.klist, p.misc, p.orig,
                         p.xs, nullptr, 0, tok, dst, Atile, tid);
    }
    grid.sync();

    // ---------- Phase E: persistent LSTM (v8 structure, verbatim) ----------
    {
        const short* xsl = p.xs;
        const short* wc = p.wcb;
        short* hstore = p.hs;
        if (tid < 8) {
            int s = p.grp[bid * 8 + tid];
            s_off[tid] = p.seqo[s];
            s_len[tid] = p.lens[s];
        }
        for (int j = tid; j < 11 * 8 * 136; j += TPB) hchunk[j] = 0;
        __syncthreads();
        int lane = tid & 63, l15 = lane & 15, ql = lane >> 4;
        int wave = tid >> 6;
        int u = wave * 16 + l15;
        short* hb = hchunk;
        bf16x8 Bf[4][8];
        #pragma unroll
        for (int g = 0; g < 4; g++) {
            int j = g * 128 + u;
            #pragma unroll
            for (int kt = 0; kt < 8; kt++)
                Bf[g][kt] = *(const bf16x8*)(wc + j * 256 + kt * 32 + ql * 8);
        }
        int maxlen = 0;
        #pragma unroll
        for (int i = 0; i < 8; i++) maxlen = max(maxlen, s_len[i]);
        int my_off = (l15 < 8) ? s_off[l15] : 0;
        int my_len = (l15 < 8) ? s_len[l15] : 1;
        bool lo = (ql < 2);
        int rowA = lo ? (ql * 4 + 0) : ((ql - 2) * 4 + 2);
        int rowB = lo ? (ql * 4 + 1) : ((ql - 2) * 4 + 3);
        int lenA = s_len[rowA], lenB = s_len[rowB];
        float cA = 0.f, cB = 0.f;
        bf16x8 Pf0[4], Pf1[4];
        #pragma unroll
        for (int k = 0; k < 4; k++) { Pf0[k] = (bf16x8){0,0,0,0,0,0,0,0}; Pf1[k] = Pf0[k]; }
        int xoff = my_off * DIM + ql * 8;
        if (l15 < 8) {
            const short* xp = xsl + xoff;
            Pf0[0] = *(const bf16x8*)(xp);      Pf0[1] = *(const bf16x8*)(xp + 32);
            Pf0[2] = *(const bf16x8*)(xp + 64); Pf0[3] = *(const bf16x8*)(xp + 96);
        }
        int xoff1 = xoff + ((my_len > 1) ? DIM : 0);
        if (l15 < 8) {
            const short* xp = xsl + xoff1;
            Pf1[0] = *(const bf16x8*)(xp);      Pf1[1] = *(const bf16x8*)(xp + 32);
            Pf1[2] = *(const bf16x8*)(xp + 64); Pf1[3] = *(const bf16x8*)(xp + 96);
        }
        xoff = xoff1 + ((my_len > 2) ? DIM : 0);

        int nb8 = (maxlen + 7) >> 3;
        for (int ob = 0; ob < nb8; ob++) {
            int ib8 = ob * 8;
            LSTM_STEP(0, Pf0)
            LSTM_STEP(1, Pf1)
            LSTM_STEP(2, Pf0)
            LSTM_STEP(3, Pf1)
            LSTM_STEP(4, Pf0)
            LSTM_STEP(5, Pf1)
            LSTM_STEP(6, Pf0)
            LSTM_STEP(7, Pf1)
            #pragma unroll
            for (int it = 0; it < 2; it++) {
                int idx = tid + it * TPB;
                int st = idx >> 7, s = (idx >> 4) & 7, part = idx & 15;
                int ig = ib8 + st;
                if (ig < s_len[s]) {
                    i32x4 v = *(const i32x4*)&hchunk[st * 1088 + s * 136 + part * 8];
                    *(i32x4*)(hstore + (size_t)(s_off[s] + ig) * DIM + part * 8) = v;
                }
            }
            __syncthreads();
        }
    }
    grid.sync();

    // ---------- Phase F: gather projection (bucketed GEMM, mode 1, atomics) ----------
    {
        int choff[NK + 1];
        #pragma unroll
        for (int j = 0; j <= NK; j++) choff[j] = p.misc[48 + j];
        int nchunks = choff[NK];
        for (int c = bid; c < nchunks; c += NBLK)
            bucket_chunk(c, choff, p.hs, p.gwb, p.klist, p.misc, p.orig,
                         nullptr, p.acc, 1, tok, dst, Atile, tid);
    }
    grid.sync();

    // ---------- Phase G: residual + LayerNorm ----------
    {
        int wave = tid >> 6, lane = tid & 63;
        for (int pass = 0; pass < 8; pass++) {
            int e = bid * 8 + wave + pass * 2048;
            const float2* a2 = (const float2*)(p.acc + (size_t)e * DIM);
            const float2* e2 = (const float2*)(p.ev + (size_t)e * DIM);
            float2 av = a2[lane], ev = e2[lane];
            float x0 = av.x + ev.x, x1 = av.y + ev.y;
            float sm = x0 + x1, sq = x0 * x0 + x1 * x1;
            #pragma unroll
            for (int m = 1; m < 64; m <<= 1) {
                sm += __shfl_xor(sm, m, 64);
                sq += __shfl_xor(sq, m, 64);
            }
            float mean = sm * (1.f / DIM);
            float var = sq * (1.f / DIM) - mean * mean;
            float rs = rsqrtf(var + 1e-5f);
            float2 gv = ((const float2*)p.lng)[lane], bv = ((const float2*)p.lnb)[lane];
            float2 ov;
            ov.x = (x0 - mean) * rs * gv.x + bv.x;
            ov.y = (x1 - mean) * rs * gv.y + bv.y;
            ((float2*)(p.out + (size_t)e * DIM))[lane] = ov;
        }
    }
}

extern "C" void kernel_launch(void* const* d_in, const int* in_sizes, int n_in,
                              void* d_out, int out_size, void* d_ws, size_t ws_size,
                              hipStream_t stream) {
    char* ws = (char*)d_ws;
    MegaParams p;
    p.ev    = (const float*)d_in[0];
    p.sw    = (const float*)d_in[1];
    p.gw    = (const float*)d_in[2];
    p.wih   = (const float*)d_in[3];
    p.whh   = (const float*)d_in[4];
    p.lng   = (const float*)d_in[5];
    p.lnb   = (const float*)d_in[6];
    p.pos   = (const int*)d_in[7];
    p.orig  = (const int*)d_in[8];
    p.lens  = (const int*)d_in[9];
    p.evb   = (short*)(ws + OFF_EV);
    p.wcb   = (short*)(ws + OFF_WC);
    p.swb   = (short*)(ws + OFF_SCAT);
    p.gwb   = (short*)(ws + OFF_GATH);
    p.xs    = (short*)(ws + OFF_XS);
    p.hs    = (short*)(ws + OFF_HS);
    p.klist = (int*)(ws + OFF_KLIST);
    p.acc   = (float*)(ws + OFF_ACC);
    p.seqo  = (int*)(ws + OFF_SEQOFF);
    p.grp   = (int*)(ws + OFF_GROUP);
    p.misc  = (int*)(ws + OFF_MISC);
    p.bh    = (int*)(ws + OFF_BH);
    p.out   = (float*)d_out;

    void* kargs[] = { (void*)&p };
    hipLaunchCooperativeKernel((const void*)mega_kernel, dim3(NBLK), dim3(TPB),
                               kargs, 0, stream);
}

// Round 10
// 300.314 us; speedup vs baseline: 1.6878x; 1.6878x over previous
//
#include <hip/hip_runtime.h>

#define N_EVENTS 16384
#define DIM 128
#define NK 9
#define NSEQ 2048
#define TT 147456
#define CHUNK 64
#define NCHUNK_MAX (TT/CHUNK + NK)   // 2313
#define NHBLK 576                    // TT / 256 exactly

typedef __attribute__((ext_vector_type(8))) short bf16x8;
typedef __attribute__((ext_vector_type(4))) float f32x4;
typedef __attribute__((ext_vector_type(4))) int i32x4;

// ---- workspace layout (bytes) ----
#define OFF_EV     0UL                                     // events bf16
#define OFF_WC     (OFF_EV   + (size_t)N_EVENTS*DIM*2)     // [w_ih|w_hh] bf16
#define OFF_SCAT   (OFF_WC   + (size_t)512*256*2)
#define OFF_GATH   (OFF_SCAT + (size_t)NK*DIM*DIM*2)
#define OFF_XS     (OFF_GATH + (size_t)NK*DIM*DIM*2)       // xs bf16; REUSED as o_flat after lstm
#define OFF_HS     (OFF_XS   + (size_t)TT*DIM*2)
#define OFF_KLIST  (OFF_HS   + (size_t)TT*DIM*2)
#define OFF_ECNT   (OFF_KLIST+ (size_t)TT*4)               // event hist: 16384
#define OFF_EOFF   (OFF_ECNT + 16384UL*4)                  // event offsets: 16385
#define OFF_ECNT2  (OFF_EOFF + 16392UL*4)                  // event rank counters
#define OFF_ELIST  (OFF_ECNT2+ 16384UL*4)                  // event-sorted tokens: TT
#define OFF_SEQOFF (OFF_ELIST+ (size_t)TT*4)
#define OFF_GROUP  (OFF_SEQOFF + (size_t)NSEQ*4)
#define OFF_MISC   (OFF_GROUP  + (size_t)NSEQ*4)
#define OFF_BH     (OFF_MISC   + 256UL)                    // blockhist: 576*9 ints
// misc ints: [0..8]=kcount  [32..40]=koff  [48..57]=choff

__device__ __forceinline__ short f2b(float f) {
    union { float f; unsigned u; } v; v.f = f;
    unsigned r = (v.u + 0x7FFFu + ((v.u >> 16) & 1u)) >> 16;
    return (short)r;
}
__device__ __forceinline__ float asf(unsigned u) {
    union { unsigned u; float f; } v; v.u = u; return v.f;
}
// raw v_rcp_f32 — avoids HIP's ~10-instr IEEE divide (the R8 win)
__device__ __forceinline__ float fsig(float x) {
    return __builtin_amdgcn_rcpf(1.f + __expf(-x));
}
__device__ __forceinline__ float ftanh(float x) {
    return 1.f - 2.f * __builtin_amdgcn_rcpf(__expf(2.f * x) + 1.f);
}

// convert to bf16 + zero the two event-counter arrays
__global__ void convert_kernel(const float* __restrict__ ev, const float* __restrict__ wih,
                               const float* __restrict__ whh, const float* __restrict__ sw,
                               const float* __restrict__ gw,
                               short* __restrict__ evb, short* __restrict__ wcb,
                               short* __restrict__ swb, short* __restrict__ gwb,
                               int* __restrict__ ecnt, int* __restrict__ ecnt2) {
    int idx = blockIdx.x * blockDim.x + threadIdx.x;
    if (idx < N_EVENTS * DIM) evb[idx] = f2b(ev[idx]);
    if (idx < 512 * DIM) {
        int j = idx >> 7, d = idx & 127;
        wcb[j * 256 + d]       = f2b(wih[idx]);
        wcb[j * 256 + 128 + d] = f2b(whh[idx]);
    }
    if (idx < NK * DIM * DIM) { swb[idx] = f2b(sw[idx]); gwb[idx] = f2b(gw[idx]); }
    if (idx < N_EVENTS) { ecnt[idx] = 0; ecnt2[idx] = 0; }
}

// k histogram (LDS) + event histogram (global, ~9-way contention)
__global__ void hist_kernel(const int* __restrict__ pos, const int* __restrict__ orig,
                            int* __restrict__ blockhist, int* __restrict__ ecnt) {
    __shared__ int h[NK];
    int tid = threadIdx.x;
    if (tid < NK) h[tid] = 0;
    __syncthreads();
    int t = blockIdx.x * 256 + tid;
    atomicAdd(&h[pos[t]], 1);
    atomicAdd(&ecnt[orig[t]], 1);
    __syncthreads();
    if (tid < NK) blockhist[blockIdx.x * NK + tid] = h[tid];
}

// 3-role planning kernel: block0 = k-bin scan, block1 = seq setup, block2 = event scan
__global__ void plan_kernel(int* __restrict__ blockhist, int* __restrict__ misc,
                            const int* __restrict__ lengths, int* __restrict__ seq_off,
                            int* __restrict__ grouped,
                            const int* __restrict__ ecnt, int* __restrict__ eoff) {
    int tid = threadIdx.x;
    if (blockIdx.x == 0) {
        __shared__ int h[NHBLK * NK];
        for (int i = tid; i < NHBLK * NK; i += 256) h[i] = blockhist[i];
        __syncthreads();
        if (tid < NK) {
            int run = 0;
            for (int b = 0; b < NHBLK; b++) {
                int v = h[b * NK + tid];
                h[b * NK + tid] = run;
                run += v;
            }
            misc[tid] = run;
        }
        __syncthreads();
        if (tid == 0) {
            int ko = 0, co = 0;
            for (int k = 0; k < NK; k++) {
                int c = misc[k];
                misc[32 + k] = ko;
                misc[48 + k] = co;
                ko += c;
                co += (c + CHUNK - 1) / CHUNK;
            }
            misc[48 + NK] = co;
        }
        __syncthreads();
        for (int i = tid; i < NHBLK * NK; i += 256) blockhist[i] = h[i];
    } else if (blockIdx.x == 1) {
        __shared__ int lens[NSEQ];
        __shared__ int tsum[256], tlong[256];
        for (int i = tid; i < NSEQ; i += 256) lens[i] = lengths[i];
        __syncthreads();
        int base = tid * 8;
        int ls[8]; int s = 0, lc = 0;
        #pragma unroll
        for (int i = 0; i < 8; i++) { ls[i] = lens[base + i]; s += ls[i]; lc += (ls[i] > 64) ? 1 : 0; }
        tsum[tid] = s; tlong[tid] = lc;
        __syncthreads();
        for (int d = 1; d < 256; d <<= 1) {
            int a = (tid >= d) ? tsum[tid - d] : 0;
            int b = (tid >= d) ? tlong[tid - d] : 0;
            __syncthreads();
            tsum[tid] += a; tlong[tid] += b;
            __syncthreads();
        }
        int nlong_total = tlong[255];
        int excl = tsum[tid] - s;
        int excl_long = tlong[tid] - lc;
        int run = 0, runl = 0;
        #pragma unroll
        for (int i = 0; i < 8; i++) {
            int sid = base + i;
            seq_off[sid] = excl + run;
            int lb = excl_long + runl;
            if (ls[i] > 64) { grouped[lb] = sid; runl++; }
            else            { grouped[nlong_total + (sid - lb)] = sid; }
            run += ls[i];
        }
    } else {
        // event scan: 16384 bins, 64 per thread
        __shared__ int part[256];
        int base = tid * 64;
        int s = 0;
        for (int j = 0; j < 64; j++) s += ecnt[base + j];
        part[tid] = s;
        __syncthreads();
        for (int d = 1; d < 256; d <<= 1) {
            int a = (tid >= d) ? part[tid - d] : 0;
            __syncthreads();
            part[tid] += a;
            __syncthreads();
        }
        int run = part[tid] - s;
        for (int j = 0; j < 64; j++) {
            eoff[base + j] = run;
            run += ecnt[base + j];
        }
        if (tid == 255) eoff[N_EVENTS] = run;
    }
}

// scatter tokens to k-sorted klist (LDS rank) + event-sorted elist (global rank)
__global__ void fill_kernel(const int* __restrict__ pos, const int* __restrict__ orig,
                            const int* __restrict__ blockhist, const int* __restrict__ misc,
                            int* __restrict__ klist,
                            const int* __restrict__ eoff, int* __restrict__ ecnt2,
                            int* __restrict__ elist) {
    __shared__ int off[NK];
    int tid = threadIdx.x;
    if (tid < NK) off[tid] = misc[32 + tid] + blockhist[blockIdx.x * NK + tid];
    __syncthreads();
    int t = blockIdx.x * 256 + tid;
    int p = atomicAdd(&off[pos[t]], 1);
    klist[p] = t;
    int o = orig[t];
    int p2 = atomicAdd(&ecnt2[o], 1);
    elist[eoff[o] + p2] = t;
}

// bucketed position-projection GEMM
// mode 0: A rows = evb[orig[tok]], out rows -> xs[tok]   (bf16)
// mode 1: A rows = hs[tok],        out rows -> o_flat[tok] (bf16) — NO atomics
__global__ void bucket_gemm(const short* __restrict__ src, const short* __restrict__ wall,
                            const int* __restrict__ klist, const int* __restrict__ misc,
                            const int* __restrict__ orig, short* __restrict__ rows_out,
                            int mode) {
    const int* chunkoff = misc + 48;
    int b = blockIdx.x;
    if (b >= chunkoff[NK]) return;
    int k = 0;
    while (k < NK - 1 && chunkoff[k + 1] <= b) k++;
    int lc = b - chunkoff[k];
    int cnt = misc[k];
    int base = misc[32 + k] + lc * CHUNK;
    int nv = min(CHUNK, cnt - lc * CHUNK);

    __shared__ int tok[CHUNK], ridx[CHUNK];
    __shared__ short A[CHUNK * 136];
    int tid = threadIdx.x;
    if (tid < CHUNK) {
        int tv = klist[base + ((tid < nv) ? tid : 0)];
        tok[tid] = tv;
        ridx[tid] = (mode == 0) ? orig[tv] : tv;
    }
    __syncthreads();
    {
        int row = tid >> 2, part = tid & 3;
        const i32x4* s4 = (const i32x4*)(src + (size_t)ridx[row] * DIM + part * 32);
        i32x4* d4 = (i32x4*)(A + row * 136 + part * 32);
        d4[0] = s4[0]; d4[1] = s4[1]; d4[2] = s4[2]; d4[3] = s4[3];
    }
    __syncthreads();
    int wave = tid >> 6, lane = tid & 63, l15 = lane & 15, q = lane >> 4;
    const short* wk = wall + (size_t)k * DIM * DIM;
    bf16x8 Bf[2][4];
    #pragma unroll
    for (int nt = 0; nt < 2; nt++) {
        int h = wave * 32 + nt * 16 + l15;
        #pragma unroll
        for (int kt = 0; kt < 4; kt++)
            Bf[nt][kt] = *(const bf16x8*)(wk + h * DIM + kt * 32 + q * 8);
    }
    f32x4 C[4][2];
    #pragma unroll
    for (int mt = 0; mt < 4; mt++)
        #pragma unroll
        for (int nt = 0; nt < 2; nt++) C[mt][nt] = (f32x4){0.f, 0.f, 0.f, 0.f};
    #pragma unroll
    for (int mt = 0; mt < 4; mt++) {
        bf16x8 Afr[4];
        const short* ar = A + (mt * 16 + l15) * 136 + q * 8;
        Afr[0] = *(const bf16x8*)(ar);
        Afr[1] = *(const bf16x8*)(ar + 32);
        Afr[2] = *(const bf16x8*)(ar + 64);
        Afr[3] = *(const bf16x8*)(ar + 96);
        #pragma unroll
        for (int nt = 0; nt < 2; nt++)
            #pragma unroll
            for (int kt = 0; kt < 4; kt++)
                C[mt][nt] = __builtin_amdgcn_mfma_f32_16x16x32_bf16(Afr[kt], Bf[nt][kt], C[mt][nt], 0, 0, 0);
    }
    __syncthreads();
    #pragma unroll
    for (int mt = 0; mt < 4; mt++)
        #pragma unroll
        for (int nt = 0; nt < 2; nt++)
            #pragma unroll
            for (int r = 0; r < 4; r++) {
                int row = mt * 16 + q * 4 + r;
                int col = wave * 32 + nt * 16 + l15;
                A[row * 136 + col] = f2b(C[mt][nt][r]);
            }
    __syncthreads();
    {
        int row = tid >> 2, part = tid & 3;
        if (row < nv) {
            const i32x4* s4 = (const i32x4*)(A + row * 136 + part * 32);
            i32x4* d4 = (i32x4*)(rows_out + (size_t)tok[row] * DIM + part * 32);
            d4[0] = s4[0]; d4[1] = s4[1]; d4[2] = s4[2]; d4[3] = s4[3];
        }
    }
}

#define MF(a, b, c) __builtin_amdgcn_mfma_f32_16x16x32_bf16(a, b, c, 0, 0, 0)

// One LSTM step, fully compile-time slot J (0..7) — v8 verbatim.
#define LSTM_STEP(J, PF) { \
    const int i_ = ib8 + (J); \
    f32x4 Cxi = {0.f,0.f,0.f,0.f}, Cxf = {0.f,0.f,0.f,0.f}; \
    f32x4 Cxg = {0.f,0.f,0.f,0.f}, Cxo = {0.f,0.f,0.f,0.f}; \
    Cxi = MF(PF[0], Bf[0][0], Cxi); Cxf = MF(PF[0], Bf[1][0], Cxf); \
    Cxg = MF(PF[0], Bf[2][0], Cxg); Cxo = MF(PF[0], Bf[3][0], Cxo); \
    Cxi = MF(PF[1], Bf[0][1], Cxi); Cxf = MF(PF[1], Bf[1][1], Cxf); \
    Cxg = MF(PF[1], Bf[2][1], Cxg); Cxo = MF(PF[1], Bf[3][1], Cxo); \
    Cxi = MF(PF[2], Bf[0][2], Cxi); Cxf = MF(PF[2], Bf[1][2], Cxf); \
    Cxg = MF(PF[2], Bf[2][2], Cxg); Cxo = MF(PF[2], Bf[3][2], Cxo); \
    Cxi = MF(PF[3], Bf[0][3], Cxi); Cxf = MF(PF[3], Bf[1][3], Cxf); \
    Cxg = MF(PF[3], Bf[2][3], Cxg); Cxo = MF(PF[3], Bf[3][3], Cxo); \
    bf16x8 Hf0, Hf1, Hf2, Hf3; \
    { const short* hp_ = hb + (((J) + 7) & 7) * 1088 + l15 * 136 + ql * 8; \
      Hf0 = *(const bf16x8*)(hp_);      Hf1 = *(const bf16x8*)(hp_ + 32); \
      Hf2 = *(const bf16x8*)(hp_ + 64); Hf3 = *(const bf16x8*)(hp_ + 96); } \
    f32x4 Chi = {0.f,0.f,0.f,0.f}, Chf = {0.f,0.f,0.f,0.f}; \
    f32x4 Chg = {0.f,0.f,0.f,0.f}, Cho = {0.f,0.f,0.f,0.f}; \
    Chi = MF(Hf0, Bf[0][4], Chi); Chf = MF(Hf0, Bf[1][4], Chf); \
    Chg = MF(Hf0, Bf[2][4], Chg); Cho = MF(Hf0, Bf[3][4], Cho); \
    Chi = MF(Hf1, Bf[0][5], Chi); Chf = MF(Hf1, Bf[1][5], Chf); \
    Chg = MF(Hf1, Bf[2][5], Chg); Cho = MF(Hf1, Bf[3][5], Cho); \
    Chi = MF(Hf2, Bf[0][6], Chi); Chf = MF(Hf2, Bf[1][6], Chf); \
    Chg = MF(Hf2, Bf[2][6], Chg); Cho = MF(Hf2, Bf[3][6], Cho); \
    Chi = MF(Hf3, Bf[0][7], Chi); Chf = MF(Hf3, Bf[1][7], Chf); \
    Chg = MF(Hf3, Bf[2][7], Chg); Cho = MF(Hf3, Bf[3][7], Cho); \
    if (l15 < 8) { \
        const short* xp_ = xs + xoff; \
        PF[0] = *(const bf16x8*)(xp_);      PF[1] = *(const bf16x8*)(xp_ + 32); \
        PF[2] = *(const bf16x8*)(xp_ + 64); PF[3] = *(const bf16x8*)(xp_ + 96); \
    } \
    xoff += ((i_ + 4) <= my_len) ? DIM : 0; \
    f32x4 Gi = Cxi + Chi, Gf = Cxf + Chf, Gg = Cxg + Chg, Go = Cxo + Cho; \
    { \
        int src_ = lane & 31; \
        float i2 = __shfl(Gi[2], src_, 64), i3 = __shfl(Gi[3], src_, 64); \
        float f2 = __shfl(Gf[2], src_, 64), f3 = __shfl(Gf[3], src_, 64); \
        float g2 = __shfl(Gg[2], src_, 64), g3 = __shfl(Gg[3], src_, 64); \
        float o2 = __shfl(Go[2], src_, 64), o3 = __shfl(Go[3], src_, 64); \
        float iA = lo ? Gi[0] : i2, iB = lo ? Gi[1] : i3; \
        float fA = lo ? Gf[0] : f2, fB = lo ? Gf[1] : f3; \
        float gA = lo ? Gg[0] : g2, gB = lo ? Gg[1] : g3; \
        float oA = lo ? Go[0] : o2, oB = lo ? Go[1] : o3; \
        if (i_ < lenA) { \
            float si = fsig(iA), sf = fsig(fA), so = fsig(oA); \
            float tg = ftanh(gA); \
            float cn = sf * cA + si * tg; \
            float th = ftanh(cn); \
            cA = cn; \
            hb[(J) * 1088 + rowA * 136 + u] = f2b(so * th); \
        } \
        if (i_ < lenB) { \
            float si = fsig(iB), sf = fsig(fB), so = fsig(oB); \
            float tg = ftanh(gB); \
            float cn = sf * cB + si * tg; \
            float th = ftanh(cn); \
            cB = cn; \
            hb[(J) * 1088 + rowB * 136 + u] = f2b(so * th); \
        } \
    } \
    __syncthreads(); \
}

// Persistent per-sequence LSTM — v8 verbatim (best measured: 135 us).
__global__ __launch_bounds__(512, 2) void lstm_kernel(
        const short* __restrict__ xs, const short* __restrict__ wc,
        short* __restrict__ hstore, const int* __restrict__ seq_off,
        const int* __restrict__ grouped, const int* __restrict__ lengths) {
    __shared__ int s_off[8], s_len[8];
    __shared__ short hchunk[11][8][136];
    int tid = threadIdx.x;
    if (tid < 8) {
        int s = grouped[blockIdx.x * 8 + tid];
        s_off[tid] = seq_off[s];
        s_len[tid] = lengths[s];
    }
    for (int j = tid; j < 11 * 8 * 136; j += 512) ((short*)hchunk)[j] = 0;
    __syncthreads();
    int lane = tid & 63, l15 = lane & 15, ql = lane >> 4;
    int wave = tid >> 6;
    int u = wave * 16 + l15;
    short* hb = (short*)hchunk;
    bf16x8 Bf[4][8];
    #pragma unroll
    for (int g = 0; g < 4; g++) {
        int j = g * 128 + u;
        #pragma unroll
        for (int kt = 0; kt < 8; kt++)
            Bf[g][kt] = *(const bf16x8*)(wc + j * 256 + kt * 32 + ql * 8);
    }
    int maxlen = 0;
    #pragma unroll
    for (int i = 0; i < 8; i++) maxlen = max(maxlen, s_len[i]);
    int my_off = (l15 < 8) ? s_off[l15] : 0;
    int my_len = (l15 < 8) ? s_len[l15] : 1;
    bool lo = (ql < 2);
    int rowA = lo ? (ql * 4 + 0) : ((ql - 2) * 4 + 2);
    int rowB = lo ? (ql * 4 + 1) : ((ql - 2) * 4 + 3);
    int lenA = s_len[rowA], lenB = s_len[rowB];
    float cA = 0.f, cB = 0.f;
    bf16x8 Pf0[4], Pf1[4];
    #pragma unroll
    for (int k = 0; k < 4; k++) { Pf0[k] = (bf16x8){0,0,0,0,0,0,0,0}; Pf1[k] = Pf0[k]; }
    int xoff = my_off * DIM + ql * 8;
    if (l15 < 8) {
        const short* xp = xs + xoff;
        Pf0[0] = *(const bf16x8*)(xp);      Pf0[1] = *(const bf16x8*)(xp + 32);
        Pf0[2] = *(const bf16x8*)(xp + 64); Pf0[3] = *(const bf16x8*)(xp + 96);
    }
    int xoff1 = xoff + ((my_len > 1) ? DIM : 0);
    if (l15 < 8) {
        const short* xp = xs + xoff1;
        Pf1[0] = *(const bf16x8*)(xp);      Pf1[1] = *(const bf16x8*)(xp + 32);
        Pf1[2] = *(const bf16x8*)(xp + 64); Pf1[3] = *(const bf16x8*)(xp + 96);
    }
    xoff = xoff1 + ((my_len > 2) ? DIM : 0);

    int nb8 = (maxlen + 7) >> 3;
    for (int ob = 0; ob < nb8; ob++) {
        int ib8 = ob * 8;
        LSTM_STEP(0, Pf0)
        LSTM_STEP(1, Pf1)
        LSTM_STEP(2, Pf0)
        LSTM_STEP(3, Pf1)
        LSTM_STEP(4, Pf0)
        LSTM_STEP(5, Pf1)
        LSTM_STEP(6, Pf0)
        LSTM_STEP(7, Pf1)
        #pragma unroll
        for (int it = 0; it < 2; it++) {
            int idx = tid + it * 512;
            int st = idx >> 7, s = (idx >> 4) & 7, part = idx & 15;
            int ig = ib8 + st;
            if (ig < s_len[s]) {
                i32x4 v = *(const i32x4*)&hchunk[st][s][part * 8];
                *(i32x4*)(hstore + (size_t)(s_off[s] + ig) * DIM + part * 8) = v;
            }
        }
        __syncthreads();
    }
}

// gather each event's token rows (CSR) + residual + LayerNorm
__global__ void gather_ln(const short* __restrict__ of, const int* __restrict__ eoff,
                          const int* __restrict__ elist, const float* __restrict__ ev,
                          const float* __restrict__ g, const float* __restrict__ bta,
                          float* __restrict__ out) {
    int tid = threadIdx.x;
    int wave = tid >> 6, lane = tid & 63;
    int e = blockIdx.x * 4 + wave;
    int s0 = eoff[e], s1 = eoff[e + 1];
    float x0 = 0.f, x1 = 0.f;
    for (int j = s0; j < s1; j++) {
        int t = elist[j];
        unsigned v = *(const unsigned*)(of + (size_t)t * DIM + lane * 2);
        x0 += asf(v << 16);
        x1 += asf(v & 0xffff0000u);
    }
    const float2* e2 = (const float2*)(ev + (size_t)e * DIM);
    float2 evv = e2[lane];
    x0 += evv.x; x1 += evv.y;
    float sm = x0 + x1, sq = x0 * x0 + x1 * x1;
    #pragma unroll
    for (int m = 1; m < 64; m <<= 1) {
        sm += __shfl_xor(sm, m, 64);
        sq += __shfl_xor(sq, m, 64);
    }
    float mean = sm * (1.f / DIM);
    float var = sq * (1.f / DIM) - mean * mean;
    float rs = rsqrtf(var + 1e-5f);
    float2 gv = ((const float2*)g)[lane], bv = ((const float2*)bta)[lane];
    float2 ov;
    ov.x = (x0 - mean) * rs * gv.x + bv.x;
    ov.y = (x1 - mean) * rs * gv.y + bv.y;
    ((float2*)(out + (size_t)e * DIM))[lane] = ov;
}

extern "C" void kernel_launch(void* const* d_in, const int* in_sizes, int n_in,
                              void* d_out, int out_size, void* d_ws, size_t ws_size,
                              hipStream_t stream) {
    const float* events = (const float*)d_in[0];
    const float* scat   = (const float*)d_in[1];
    const float* gath   = (const float*)d_in[2];
    const float* wih    = (const float*)d_in[3];
    const float* whh    = (const float*)d_in[4];
    const float* lng    = (const float*)d_in[5];
    const float* lnb    = (const float*)d_in[6];
    const int* posid    = (const int*)d_in[7];
    const int* orig     = (const int*)d_in[8];
    const int* lens     = (const int*)d_in[9];
    char* ws = (char*)d_ws;
    short* evb   = (short*)(ws + OFF_EV);
    short* wcb   = (short*)(ws + OFF_WC);
    short* swb   = (short*)(ws + OFF_SCAT);
    short* gwb   = (short*)(ws + OFF_GATH);
    short* xs    = (short*)(ws + OFF_XS);      // also o_flat (xs dead after lstm)
    short* hs    = (short*)(ws + OFF_HS);
    int*   klist = (int*)(ws + OFF_KLIST);
    int*   ecnt  = (int*)(ws + OFF_ECNT);
    int*   eoff  = (int*)(ws + OFF_EOFF);
    int*   ecnt2 = (int*)(ws + OFF_ECNT2);
    int*   elist = (int*)(ws + OFF_ELIST);
    int*   seqo  = (int*)(ws + OFF_SEQOFF);
    int*   grp   = (int*)(ws + OFF_GROUP);
    int*   misc  = (int*)(ws + OFF_MISC);
    int*   bh    = (int*)(ws + OFF_BH);
    float* out   = (float*)d_out;

    convert_kernel<<<8192, 256, 0, stream>>>(events, wih, whh, scat, gath,
                                             evb, wcb, swb, gwb, ecnt, ecnt2);
    hist_kernel<<<NHBLK, 256, 0, stream>>>(posid, orig, bh, ecnt);
    plan_kernel<<<3, 256, 0, stream>>>(bh, misc, lens, seqo, grp, ecnt, eoff);
    fill_kernel<<<NHBLK, 256, 0, stream>>>(posid, orig, bh, misc, klist, eoff, ecnt2, elist);
    bucket_gemm<<<NCHUNK_MAX, 256, 0, stream>>>(evb, swb, klist, misc, orig, xs, 0);
    lstm_kernel<<<256, 512, 0, stream>>>(xs, wcb, hs, seqo, grp, lens);
    bucket_gemm<<<NCHUNK_MAX, 256, 0, stream>>>(hs, gwb, klist, misc, orig, xs, 1);
    gather_ln<<<4096, 256, 0, stream>>>(xs, eoff, elist, events, lng, lnb, out);
}